// Round 22
// baseline (73.429 us; speedup 1.0000x reference)
//
#include <hip/hip_runtime.h>
#include <hip/hip_bf16.h>
#include <hip/hip_fp16.h>

#define B_TOT 65536
#define S 9
#define D 20
#define DFF 512
#define EPS 1e-5f
// score scale folded into Wq/bq at prep: exp(qk/3) == exp2(qk * log2(e)/3)
#define QSCALE 0.48089834696298783f

typedef short bf16x8 __attribute__((ext_vector_type(8)));
typedef _Float16 f16x8 __attribute__((ext_vector_type(8)));
typedef float f32x4 __attribute__((ext_vector_type(4)));

// ws layout (short idx unless noted) — r18 geometry:
//   PQKV [4ct][64][8] bf16 @ 0     : A-frags of [Wq|Wk|Wv]^T unpadded (j 0..59); Wq pre-scaled by QSCALE
//   PWOA [2ct][64][8] bf16 @ 2048  : A-frags of Wo^T
//   BQKV f32[64] @ float 1536      : bq*QSCALE|bk|bv concat
//   BO4  f32[64] @ float 1600      : bo padded
//   PA1  [32frag][64][8] bf16 @ 3328 : W1 A-frags, PERMUTED (verified)
//   PB2  [32frag][64][8] f16  @ 19712: W2 B-frags (f16; FFN2 = f16 MFMA)
#define SH_PQKV 0
#define SH_PWOA 2048
#define FL_BQKV 1536
#define FL_BO4 1600
#define SH_PA1 3328
#define SH_PB2 19712
#define PREP_TOTAL (2048 + 1024 + 128 + 16384 + 16384)

__device__ __forceinline__ unsigned short f2bf(float f) {
  union { __hip_bfloat16 h; unsigned short u; } v;
  v.h = __float2bfloat16(f);
  return v.u;
}
__device__ __forceinline__ unsigned short f2h(float f) {
  union { _Float16 h; unsigned short u; } v;
  v.h = (_Float16)f;
  return v.u;
}
__device__ __forceinline__ unsigned cvt2(float a, float b) {
  union { __hip_bfloat162 h; unsigned u; } v;
  v.h = __float22bfloat162_rn(make_float2(a, b));
  return v.u;
}
__device__ __forceinline__ unsigned cvt2h(float a, float b) {
  union { __half2 h; unsigned u; } v;
  v.h = __float22half2_rn(make_float2(a, b));
  return v.u;
}
__device__ __forceinline__ unsigned pkmax0(unsigned a, unsigned z) {
  unsigned r;
  asm("v_pk_max_f16 %0, %1, %2" : "=v"(r) : "v"(a), "v"(z));
  return r;
}

union h2u { unsigned u; __half2 h; };

__global__ void prep_kernel(const float* __restrict__ Wq, const float* __restrict__ Wk,
                            const float* __restrict__ Wv, const float* __restrict__ Wo,
                            const float* __restrict__ W1, const float* __restrict__ W2,
                            const float* __restrict__ bq, const float* __restrict__ bk,
                            const float* __restrict__ bv, const float* __restrict__ bo,
                            float* __restrict__ wsf) {
  int stride = gridDim.x * blockDim.x;
  unsigned short* P = (unsigned short*)wsf;
  for (int i = blockIdx.x * blockDim.x + threadIdx.x; i < PREP_TOTAL; i += stride) {
    if (i < 2048) {
      // PQKV unpadded: row j = ct*16+cl (0..59 used), k = d = 8g+jj
      int ct = i >> 9, rem = i & 511, l = rem >> 3, jj = rem & 7;
      int g = l >> 4, cl = l & 15;
      int j = ct * 16 + cl, d = 8 * g + jj;
      unsigned short v = 0;
      if (d < 20 && j < 60) {
        int mat = j / 20, jc = j % 20;
        const float* Wsrc = (mat == 0) ? Wq : (mat == 1) ? Wk : Wv;
        float w = Wsrc[d * 20 + jc];
        if (mat == 0) w *= QSCALE;  // fold exp2-domain score scale into Wq
        v = f2bf(w);
      }
      P[SH_PQKV + i] = v;
    } else if (i < 3072) {
      int p = i - 2048;
      int ct = p >> 9, rem = p & 511, l = rem >> 3, jj = rem & 7;
      int g = l >> 4, cl = l & 15;
      int j = ct * 16 + cl, d = 8 * g + jj;
      P[SH_PWOA + p] = (d < 20 && j < 20) ? f2bf(Wo[d * 20 + j]) : (unsigned short)0;
    } else if (i < 3200) {
      int j = i - 3072;  // 0..127
      float v = 0.f;
      if (j < 20) v = bq[j] * QSCALE;
      else if (j < 40) v = bk[j - 20];
      else if (j < 60) v = bv[j - 40];
      else if (j >= 64 && j < 84) v = bo[j - 64];
      wsf[FL_BQKV + j] = v;
    } else if (i < 3200 + 16384) {
      int j = i - 3200;
      int frag = j >> 9, rem = j & 511;
      int l = rem >> 3, jj = rem & 7;
      int p = frag & 1, q2 = (frag >> 1) & 3, ch = frag >> 3;
      int g2 = l >> 4, cl2 = l & 15;
      int k = 8 * g2 + jj;
      int f = ch * 128 + q2 * 32 + 8 * (cl2 >> 2) + 4 * p + (cl2 & 3);
      P[SH_PA1 + j] = (k < 20) ? f2bf(W1[k * DFF + f]) : (unsigned short)0;
    } else {
      // PB2 — f16 (FFN2 uses mfma_f32_16x16x32_f16)
      int j = i - (3200 + 16384);
      int pair = j >> 9, rem = j & 511;
      int l = rem >> 3, jj = rem & 7;
      int g = l >> 4, cl = l & 15;
      int kk = pair >> 1, cc = pair & 1;
      int kg = kk * 32 + 8 * g + jj;
      int d = cc * 16 + cl;
      P[SH_PB2 + j] = (d < 20) ? f2h(W2[kg * 20 + d]) : (unsigned short)0;
    }
  }
}

// ONE-WAVE workgroups (64 threads), slab 9728 B. No __syncthreads anywhere.
// X is NOT staged: B-frags load directly from global (contiguous 8-float runs),
// removing the write->read LDS round-trip at the chain head. RA holds q then Y.
//   RA @0    stride 72, 64 rows: q f16 unpadded (0..39) -> [Y bf16 40B | zeros 40..63]
//   RB @4608 stride 80, 64 rows: [k f16 40B | v f16 40B @40]
//            -> overlay: merged bf16 (0..39 + zeros to 63) -> ao f32 80B -> ff f32 80B
#define SLAB_BYTES 9728
#define RA 0
#define RB 4608

#define FENCE() asm volatile("" ::: "memory")

__global__ __launch_bounds__(64, 2) void encoder_kernel(
    const float* __restrict__ X, const float* __restrict__ ws,
    const float* __restrict__ g1, const float* __restrict__ b1,
    const float* __restrict__ g2, const float* __restrict__ b2,
    float* __restrict__ Out) {
  __shared__ __align__(16) char smem[SLAB_BYTES];

  const unsigned short* P16 = (const unsigned short*)ws;
  const unsigned short* PQKV = P16 + SH_PQKV;
  const unsigned short* PWOA = P16 + SH_PWOA;
  const float* BQKV = ws + FL_BQKV;
  const float* BO4 = ws + FL_BO4;
  const unsigned short* PA1 = P16 + SH_PA1;
  const unsigned short* PB2 = P16 + SH_PB2;

  const int lane = threadIdx.x & 63;
  const int bl = lane / 9;     // 0..7 (7 == pad lane 63)
  const int s = lane - bl * 9;
  const long wb = (long)blockIdx.x;  // one wave per block
  const long bb = wb * 7 + bl;
  const bool active = (bl < 7) && (bb < B_TOT);

  char* slab = smem;
  const int cl = lane & 15;
  const int g = lane >> 4;
  const f32x4 zero4 = {0.f, 0.f, 0.f, 0.f};
  const long rowbase = wb * 63;
  const long total_rows = (long)B_TOT * S;

  float x[20];  // residual through LN1 (regs)
  if (active) {
    const float4* xr = (const float4*)(X + bb * (S * D) + s * D);
#pragma unroll
    for (int i = 0; i < 5; ++i) {
      float4 t = xr[i];
      x[4 * i + 0] = t.x; x[4 * i + 1] = t.y; x[4 * i + 2] = t.z; x[4 * i + 3] = t.w;
    }
  } else {
#pragma unroll
    for (int i = 0; i < 20; ++i) x[i] = 0.f;
  }

  // ---------------- X B-frags DIRECT from global (no LDS staging) ------------
  // frag for lane (cl,g), rtc = X[row=rtc*16+cl][8g..8g+7] (contiguous floats);
  // elements >=20 and pad/OOB rows are zero.
  bf16x8 xfB[4];
#pragma unroll
  for (int rtc = 0; rtc < 4; ++rtc) {
    const int row = rtc * 16 + cl;
    const long grow = rowbase + row;
    const bool rv = (row < 63) && (grow < total_rows);
    union { bf16x8 v; unsigned uu[4]; } f;
    if (rv && g < 2) {
      const float4* xp = (const float4*)(X + grow * 20 + 8 * g);
      float4 a = xp[0], b = xp[1];
      f.uu[0] = cvt2(a.x, a.y); f.uu[1] = cvt2(a.z, a.w);
      f.uu[2] = cvt2(b.x, b.y); f.uu[3] = cvt2(b.z, b.w);
    } else if (rv && g == 2) {
      float4 a = *(const float4*)(X + grow * 20 + 16);
      f.uu[0] = cvt2(a.x, a.y); f.uu[1] = cvt2(a.z, a.w);
      f.uu[2] = 0u; f.uu[3] = 0u;
    } else {
      f.uu[0] = 0u; f.uu[1] = 0u; f.uu[2] = 0u; f.uu[3] = 0u;
    }
    xfB[rtc] = f.v;
  }

  // ---------------- QKV MFMA (swapped), bias C-in, f16 unpadded scatter ------
#pragma unroll
  for (int ct = 0; ct < 4; ++ct) {
    bf16x8 wf = *(const bf16x8*)(PQKV + (size_t)(ct * 64 + lane) * 8);
    float4 bq4 = *(const float4*)(BQKV + ct * 16 + 4 * g);
    const f32x4 cin = {bq4.x, bq4.y, bq4.z, bq4.w};
    const int qd = ct * 4 + g;                 // j-quad 0..15
    const int mat = (qd >= 10) ? 2 : ((qd >= 5) ? 1 : 0);
    const int jc4 = qd - 5 * mat;              // quad within matrix 0..4
    const bool qv = qd < 15;
#pragma unroll
    for (int rtc = 0; rtc < 4; ++rtc) {
      f32x4 d = __builtin_amdgcn_mfma_f32_16x16x32_bf16(wf, xfB[rtc], cin, 0, 0, 0);
      if (qv) {
        const int row = rtc * 16 + cl;
        unsigned u0 = cvt2h(d[0], d[1]);
        unsigned u1 = cvt2h(d[2], d[3]);
        char* p = (mat == 0) ? (slab + RA + row * 72 + jc4 * 8)
                             : (slab + RB + row * 80 + ((mat == 2) ? 40 : 0) + jc4 * 8);
        *(uint2*)p = make_uint2(u0, u1);
      }
    }
  }
  FENCE();

  // ---------------- attention: unpadded packed-f16, no-max exp2 softmax -------
  // pairs p cover els (2p,2p+1); heads: h0 els0-4, h1 5-9, h2 10-14, h3 15-19
  float ctx[20];
  if (active) {
    h2u q2[10];
    {
      const uint2* qp = (const uint2*)(slab + RA + lane * 72);
#pragma unroll
      for (int i = 0; i < 5; ++i) { uint2 t = qp[i]; q2[2 * i].u = t.x; q2[2 * i + 1].u = t.y; }
    }
    float sc[4][9];
#pragma unroll
    for (int t = 0; t < 9; ++t) {
      h2u k2[10];
      const char* kp = slab + RB + (bl * 9 + t) * 80;
      {
        uint4 a = *(const uint4*)kp;          // 16B aligned (80|16)
        uint4 b = *(const uint4*)(kp + 16);
        uint2 c = *(const uint2*)(kp + 32);
        k2[0].u = a.x; k2[1].u = a.y; k2[2].u = a.z; k2[3].u = a.w;
        k2[4].u = b.x; k2[5].u = b.y; k2[6].u = b.z; k2[7].u = b.w;
        k2[8].u = c.x; k2[9].u = c.y;
      }
      __half2 a0 = __hmul2(q2[0].h, k2[0].h); a0 = __hfma2(q2[1].h, k2[1].h, a0);
      __half2 m2 = __hmul2(q2[2].h, k2[2].h);
      __half2 a1 = __hmul2(q2[3].h, k2[3].h); a1 = __hfma2(q2[4].h, k2[4].h, a1);
      __half2 a2 = __hmul2(q2[5].h, k2[5].h); a2 = __hfma2(q2[6].h, k2[6].h, a2);
      __half2 m7 = __hmul2(q2[7].h, k2[7].h);
      __half2 a3 = __hmul2(q2[8].h, k2[8].h); a3 = __hfma2(q2[9].h, k2[9].h, a3);
      sc[0][t] = __low2float(a0) + __high2float(a0) + __low2float(m2);
      sc[1][t] = __high2float(m2) + __low2float(a1) + __high2float(a1);
      sc[2][t] = __low2float(a2) + __high2float(a2) + __low2float(m7);
      sc[3][t] = __high2float(m7) + __low2float(a3) + __high2float(a3);
    }
    // scores already in exp2 domain (Wq pre-scaled by log2(e)/3); |score| << 1
    // so no max-subtraction needed (softmax is shift-invariant; no overflow).
    float inv4[4];
#pragma unroll
    for (int h = 0; h < 4; ++h) {
      float sum = 0.f;
#pragma unroll
      for (int t = 0; t < 9; ++t) {
        sc[h][t] = exp2f(sc[h][t]);
        sum += sc[h][t];
      }
      inv4[h] = 1.0f / sum;
    }
    h2u ctx2[10];
#pragma unroll
    for (int i = 0; i < 10; ++i) ctx2[i].u = 0u;
#pragma unroll
    for (int t = 0; t < 9; ++t) {
      h2u v2[10];
      const char* vp = slab + RB + (bl * 9 + t) * 80 + 40;
      {
        uint2 a = *(const uint2*)vp;          // 8-aligned
        uint4 b = *(const uint4*)(vp + 8);    // +48 ≡ 0 mod 16
        uint4 c = *(const uint4*)(vp + 24);
        v2[0].u = a.x; v2[1].u = a.y;
        v2[2].u = b.x; v2[3].u = b.y; v2[4].u = b.z; v2[5].u = b.w;
        v2[6].u = c.x; v2[7].u = c.y; v2[8].u = c.z; v2[9].u = c.w;
      }
      h2u p00, p11, p22, p33, m01, m23;
      p00.h = __float2half2_rn(sc[0][t]);
      p11.h = __float2half2_rn(sc[1][t]);
      p22.h = __float2half2_rn(sc[2][t]);
      p33.h = __float2half2_rn(sc[3][t]);
      m01.u = cvt2h(sc[0][t], sc[1][t]);
      m23.u = cvt2h(sc[2][t], sc[3][t]);
      ctx2[0].h = __hfma2(p00.h, v2[0].h, ctx2[0].h);
      ctx2[1].h = __hfma2(p00.h, v2[1].h, ctx2[1].h);
      ctx2[2].h = __hfma2(m01.h, v2[2].h, ctx2[2].h);
      ctx2[3].h = __hfma2(p11.h, v2[3].h, ctx2[3].h);
      ctx2[4].h = __hfma2(p11.h, v2[4].h, ctx2[4].h);
      ctx2[5].h = __hfma2(p22.h, v2[5].h, ctx2[5].h);
      ctx2[6].h = __hfma2(p22.h, v2[6].h, ctx2[6].h);
      ctx2[7].h = __hfma2(m23.h, v2[7].h, ctx2[7].h);
      ctx2[8].h = __hfma2(p33.h, v2[8].h, ctx2[8].h);
      ctx2[9].h = __hfma2(p33.h, v2[9].h, ctx2[9].h);
    }
#pragma unroll
    for (int p = 0; p < 10; ++p) {
      ctx[2 * p] = __low2float(ctx2[p].h) * inv4[(2 * p) / 5];
      ctx[2 * p + 1] = __high2float(ctx2[p].h) * inv4[(2 * p + 1) / 5];
    }
  }
  FENCE();  // k/v reads done before merged overlay of RB

  // ---------------- merged-ctx scatter (transpose quirk), stride 80 in RB ----
  if (active) {
    int m = s;  // merged linear index m = 9*w + s, w = 5h+dh
#pragma unroll
    for (int w = 0; w < 20; ++w) {
      int row = (m * 3277) >> 16;  // m/20 (m < 180)
      int col = m - 20 * row;
      *(unsigned short*)(slab + RB + (bl * 9 + row) * 80 + col * 2) = f2bf(ctx[w]);
      m += 9;
    }
  } else {
    *(uint4*)(slab + RB + lane * 80) = make_uint4(0u, 0u, 0u, 0u);
    *(uint4*)(slab + RB + lane * 80 + 16) = make_uint4(0u, 0u, 0u, 0u);
    *(uint2*)(slab + RB + lane * 80 + 32) = make_uint2(0u, 0u);
  }
  // zero-pad merged cols 20..31 (every lane owns row `lane`)
  *(uint2*)(slab + RB + lane * 80 + 40) = make_uint2(0u, 0u);
  *(uint4*)(slab + RB + lane * 80 + 48) = make_uint4(0u, 0u, 0u, 0u);
  FENCE();

  // ---------------- Wo MFMA (swapped), bias C-in, fp32 ao scatter ------------
  bf16x8 mfB[4];
#pragma unroll
  for (int rtc = 0; rtc < 4; ++rtc)
    mfB[rtc] = *(const bf16x8*)(slab + RB + (rtc * 16 + cl) * 80 + g * 16);
  FENCE();  // merged consumed before ao overlay
#pragma unroll
  for (int ct = 0; ct < 2; ++ct) {
    bf16x8 wof = *(const bf16x8*)(PWOA + (size_t)(ct * 64 + lane) * 8);
    float4 bo4 = *(const float4*)(BO4 + ct * 16 + 4 * g);
    const f32x4 cin = {bo4.x, bo4.y, bo4.z, bo4.w};
    const int qd = ct * 4 + g;
    const bool qv = qd < 5;
#pragma unroll
    for (int rtc = 0; rtc < 4; ++rtc) {
      f32x4 d = __builtin_amdgcn_mfma_f32_16x16x32_bf16(wof, mfB[rtc], cin, 0, 0, 0);
      if (qv) {
        const int row = rtc * 16 + cl;
        *(float4*)(slab + RB + row * 80 + qd * 16) = make_float4(d[0], d[1], d[2], d[3]);
      }
    }
  }
  FENCE();

  // ---------------- LN1 (ao fp32 from LDS; x from registers) -----------------
  float y[20];
  if (active) {
    float ao[20];
    {
      const float4* ap = (const float4*)(slab + RB + lane * 80);
#pragma unroll
      for (int i = 0; i < 5; ++i) {
        float4 t = ap[i];
        ao[4 * i] = t.x; ao[4 * i + 1] = t.y; ao[4 * i + 2] = t.z; ao[4 * i + 3] = t.w;
      }
    }
    float z[20];
#pragma unroll
    for (int d = 0; d < 20; ++d) z[d] = ao[d] + x[d];
    float t0 = 0.f;
#pragma unroll
    for (int d = 0; d < 20; ++d) t0 += z[d];
    float mean = t0 * (1.0f / 20.0f);
    float var = 0.f;
#pragma unroll
    for (int d = 0; d < 20; ++d) { z[d] -= mean; var += z[d] * z[d]; }
    float rs = rsqrtf(var * (1.0f / 20.0f) + EPS);
#pragma unroll
    for (int d = 0; d < 20; ++d) y[d] = z[d] * rs * g1[d] + b1[d];
  } else {
#pragma unroll
    for (int d = 0; d < 20; ++d) y[d] = 0.f;
  }
  FENCE();  // q dead; safe to overwrite RA with Y

  // ---------------- stage Y bf16 rows + zero pad 40..63 ----------------------
  {
    char* r = slab + RA + lane * 72;
#pragma unroll
    for (int i = 0; i < 5; ++i)
      *(uint2*)(r + 8 * i) = make_uint2(cvt2(y[4 * i], y[4 * i + 1]),
                                        cvt2(y[4 * i + 2], y[4 * i + 3]));
    *(uint2*)(r + 40) = make_uint2(0u, 0u);
    *(uint2*)(r + 48) = make_uint2(0u, 0u);
    *(uint2*)(r + 56) = make_uint2(0u, 0u);
  }
  FENCE();

  // ---------------- FFN via MFMA: bf16 FFN1 -> pk_max relu -> f16 FFN2 -------
  bf16x8 ytf[4];
#pragma unroll
  for (int rt = 0; rt < 4; ++rt)
    ytf[rt] = *(const bf16x8*)(slab + RA + (rt * 16 + cl) * 72 + g * 16);

  f32x4 acc[4][2];
#pragma unroll
  for (int rt = 0; rt < 4; ++rt) { acc[rt][0] = zero4; acc[rt][1] = zero4; }

  const unsigned zz = 0u;
  for (int ch = 0; ch < 4; ++ch) {
#pragma unroll
    for (int q2 = 0; q2 < 4; ++q2) {
      const int fb = ch * 8 + q2 * 2;
      bf16x8 aw0 = *(const bf16x8*)(PA1 + (size_t)(fb * 64 + lane) * 8);
      bf16x8 aw1 = *(const bf16x8*)(PA1 + (size_t)((fb + 1) * 64 + lane) * 8);
      f16x8 bw0 = *(const f16x8*)(PB2 + (size_t)(fb * 64 + lane) * 8);
      f16x8 bw1 = *(const f16x8*)(PB2 + (size_t)((fb + 1) * 64 + lane) * 8);
#pragma unroll
      for (int rt = 0; rt < 4; ++rt) {
        f32x4 d0 = __builtin_amdgcn_mfma_f32_16x16x32_bf16(aw0, ytf[rt], zero4, 0, 0, 0);
        f32x4 d1 = __builtin_amdgcn_mfma_f32_16x16x32_bf16(aw1, ytf[rt], zero4, 0, 0, 0);
        union { f16x8 v; unsigned uu[4]; } af;
        af.uu[0] = pkmax0(cvt2h(d0[0], d0[1]), zz);
        af.uu[1] = pkmax0(cvt2h(d0[2], d0[3]), zz);
        af.uu[2] = pkmax0(cvt2h(d1[0], d1[1]), zz);
        af.uu[3] = pkmax0(cvt2h(d1[2], d1[3]), zz);
        acc[rt][0] = __builtin_amdgcn_mfma_f32_16x16x32_f16(af.v, bw0, acc[rt][0], 0, 0, 0);
        acc[rt][1] = __builtin_amdgcn_mfma_f32_16x16x32_f16(af.v, bw1, acc[rt][1], 0, 0, 0);
      }
    }
  }

  // ---------------- LN2 transposed: ff -> LDS, per-lane LN, coalesced store --
#pragma unroll
  for (int rt = 0; rt < 4; ++rt) {
#pragma unroll
    for (int r = 0; r < 4; ++r) {
      const int rrow = rt * 16 + 4 * g + r;
      *(float*)(slab + RB + rrow * 80 + cl * 4) = acc[rt][0][r];
      if (cl < 4) *(float*)(slab + RB + rrow * 80 + 64 + cl * 4) = acc[rt][1][r];
    }
  }
  FENCE();

  if (active) {
    float z[20];
    {
      const float4* fp = (const float4*)(slab + RB + lane * 80);
#pragma unroll
      for (int i = 0; i < 5; ++i) {
        float4 t = fp[i];
        z[4 * i] = t.x; z[4 * i + 1] = t.y; z[4 * i + 2] = t.z; z[4 * i + 3] = t.w;
      }
    }
    // residual y from registers
    float t0 = 0.f;
#pragma unroll
    for (int d = 0; d < 20; ++d) { z[d] += y[d]; t0 += z[d]; }
    float mean = t0 * (1.0f / 20.0f);
    float var = 0.f;
#pragma unroll
    for (int d = 0; d < 20; ++d) { z[d] -= mean; var += z[d] * z[d]; }
    float rs = rsqrtf(var * (1.0f / 20.0f) + EPS);
    float o[20];
#pragma unroll
    for (int d = 0; d < 20; ++d) o[d] = z[d] * rs * g2[d] + b2[d];
    float4* op = (float4*)(Out + (wb * 63 + lane) * 20);
#pragma unroll
    for (int i = 0; i < 5; ++i)
      op[i] = make_float4(o[4 * i], o[4 * i + 1], o[4 * i + 2], o[4 * i + 3]);
  }
}

extern "C" void kernel_launch(void* const* d_in, const int* in_sizes, int n_in,
                              void* d_out, int out_size, void* d_ws, size_t ws_size,
                              hipStream_t stream) {
  const float* X  = (const float*)d_in[0];
  const float* Wq = (const float*)d_in[1];
  const float* bq = (const float*)d_in[2];
  const float* Wk = (const float*)d_in[3];
  const float* bk = (const float*)d_in[4];
  const float* Wv = (const float*)d_in[5];
  const float* bv = (const float*)d_in[6];
  const float* Wo = (const float*)d_in[7];
  const float* bo = (const float*)d_in[8];
  const float* g1 = (const float*)d_in[9];
  const float* b1 = (const float*)d_in[10];
  const float* W1 = (const float*)d_in[11];
  const float* W2 = (const float*)d_in[12];
  const float* g2 = (const float*)d_in[13];
  const float* b2 = (const float*)d_in[14];
  float* Out = (float*)d_out;
  float* ws = (float*)d_ws;

  prep_kernel<<<144, 256, 0, stream>>>(Wq, Wk, Wv, Wo, W1, W2, bq, bk, bv, bo, ws);

  // one wave per block, 7 batch elements per wave
  int nblocks = (B_TOT + 6) / 7;  // 9363
  encoder_kernel<<<nblocks, 64, 0, stream>>>(X, ws, g1, b1, g2, b2, Out);
}

// Round 23
// 70.322 us; speedup vs baseline: 1.0442x; 1.0442x over previous
//
#include <hip/hip_runtime.h>
#include <hip/hip_bf16.h>
#include <hip/hip_fp16.h>

#define B_TOT 65536
#define S 9
#define D 20
#define DFF 512
#define EPS 1e-5f
// score scale folded into Wq/bq at prep: exp(qk/3) == exp2(qk * log2(e)/3)
#define QSCALE 0.48089834696298783f

typedef short bf16x8 __attribute__((ext_vector_type(8)));
typedef _Float16 f16x8 __attribute__((ext_vector_type(8)));
typedef float f32x4 __attribute__((ext_vector_type(4)));

// ws layout (short idx unless noted) — r18 geometry:
//   PQKV [4ct][64][8] bf16 @ 0     : A-frags of [Wq|Wk|Wv]^T unpadded (j 0..59); Wq pre-scaled by QSCALE
//   PWOA [2ct][64][8] bf16 @ 2048  : A-frags of Wo^T
//   BQKV f32[64] @ float 1536      : bq*QSCALE|bk|bv concat
//   BO4  f32[64] @ float 1600      : bo padded
//   PA1  [32frag][64][8] bf16 @ 3328 : W1 A-frags, PERMUTED (verified)
//   PB2  [32frag][64][8] f16  @ 19712: W2 B-frags (f16; FFN2 = f16 MFMA)
#define SH_PQKV 0
#define SH_PWOA 2048
#define FL_BQKV 1536
#define FL_BO4 1600
#define SH_PA1 3328
#define SH_PB2 19712
#define PREP_TOTAL (2048 + 1024 + 128 + 16384 + 16384)

__device__ __forceinline__ unsigned short f2bf(float f) {
  union { __hip_bfloat16 h; unsigned short u; } v;
  v.h = __float2bfloat16(f);
  return v.u;
}
__device__ __forceinline__ unsigned short f2h(float f) {
  union { _Float16 h; unsigned short u; } v;
  v.h = (_Float16)f;
  return v.u;
}
__device__ __forceinline__ unsigned cvt2(float a, float b) {
  union { __hip_bfloat162 h; unsigned u; } v;
  v.h = __float22bfloat162_rn(make_float2(a, b));
  return v.u;
}
__device__ __forceinline__ unsigned cvt2h(float a, float b) {
  union { __half2 h; unsigned u; } v;
  v.h = __float22half2_rn(make_float2(a, b));
  return v.u;
}
__device__ __forceinline__ unsigned pkmax0(unsigned a, unsigned z) {
  unsigned r;
  asm("v_pk_max_f16 %0, %1, %2" : "=v"(r) : "v"(a), "v"(z));
  return r;
}

union h2u { unsigned u; __half2 h; };

__global__ void prep_kernel(const float* __restrict__ Wq, const float* __restrict__ Wk,
                            const float* __restrict__ Wv, const float* __restrict__ Wo,
                            const float* __restrict__ W1, const float* __restrict__ W2,
                            const float* __restrict__ bq, const float* __restrict__ bk,
                            const float* __restrict__ bv, const float* __restrict__ bo,
                            float* __restrict__ wsf) {
  int stride = gridDim.x * blockDim.x;
  unsigned short* P = (unsigned short*)wsf;
  for (int i = blockIdx.x * blockDim.x + threadIdx.x; i < PREP_TOTAL; i += stride) {
    if (i < 2048) {
      // PQKV unpadded: row j = ct*16+cl (0..59 used), k = d = 8g+jj
      int ct = i >> 9, rem = i & 511, l = rem >> 3, jj = rem & 7;
      int g = l >> 4, cl = l & 15;
      int j = ct * 16 + cl, d = 8 * g + jj;
      unsigned short v = 0;
      if (d < 20 && j < 60) {
        int mat = j / 20, jc = j % 20;
        const float* Wsrc = (mat == 0) ? Wq : (mat == 1) ? Wk : Wv;
        float w = Wsrc[d * 20 + jc];
        if (mat == 0) w *= QSCALE;  // fold exp2-domain score scale into Wq
        v = f2bf(w);
      }
      P[SH_PQKV + i] = v;
    } else if (i < 3072) {
      int p = i - 2048;
      int ct = p >> 9, rem = p & 511, l = rem >> 3, jj = rem & 7;
      int g = l >> 4, cl = l & 15;
      int j = ct * 16 + cl, d = 8 * g + jj;
      P[SH_PWOA + p] = (d < 20 && j < 20) ? f2bf(Wo[d * 20 + j]) : (unsigned short)0;
    } else if (i < 3200) {
      int j = i - 3072;  // 0..127
      float v = 0.f;
      if (j < 20) v = bq[j] * QSCALE;
      else if (j < 40) v = bk[j - 20];
      else if (j < 60) v = bv[j - 40];
      else if (j >= 64 && j < 84) v = bo[j - 64];
      wsf[FL_BQKV + j] = v;
    } else if (i < 3200 + 16384) {
      int j = i - 3200;
      int frag = j >> 9, rem = j & 511;
      int l = rem >> 3, jj = rem & 7;
      int p = frag & 1, q2 = (frag >> 1) & 3, ch = frag >> 3;
      int g2 = l >> 4, cl2 = l & 15;
      int k = 8 * g2 + jj;
      int f = ch * 128 + q2 * 32 + 8 * (cl2 >> 2) + 4 * p + (cl2 & 3);
      P[SH_PA1 + j] = (k < 20) ? f2bf(W1[k * DFF + f]) : (unsigned short)0;
    } else {
      // PB2 — f16 (FFN2 uses mfma_f32_16x16x32_f16)
      int j = i - (3200 + 16384);
      int pair = j >> 9, rem = j & 511;
      int l = rem >> 3, jj = rem & 7;
      int g = l >> 4, cl = l & 15;
      int kk = pair >> 1, cc = pair & 1;
      int kg = kk * 32 + 8 * g + jj;
      int d = cc * 16 + cl;
      P[SH_PB2 + j] = (d < 20) ? f2h(W2[kg * 20 + d]) : (unsigned short)0;
    }
  }
}

// ONE-WAVE workgroups (64 threads), slab 9728 B. No __syncthreads anywhere.
//   RA @0    stride 72, 64 rows: [X bf16 40B | zeros 40..63] -> q f16 unpadded
//            (0..39, overlays dead X) -> [Y bf16 40B | re-zeroed 40..63]
//   RB @4608 stride 80, 64 rows: [k f16 40B | v f16 40B @40]
//            -> overlay: merged bf16 (0..39 + zeros to 63) -> ao f32 80B -> ff f32 80B
#define SLAB_BYTES 9728
#define RA 0
#define RB 4608

#define FENCE() asm volatile("" ::: "memory")

__global__ __launch_bounds__(64, 2) void encoder_kernel(
    const float* __restrict__ X, const float* __restrict__ ws,
    const float* __restrict__ g1, const float* __restrict__ b1,
    const float* __restrict__ g2, const float* __restrict__ b2,
    float* __restrict__ Out) {
  __shared__ __align__(16) char smem[SLAB_BYTES];

  const unsigned short* P16 = (const unsigned short*)ws;
  const unsigned short* PQKV = P16 + SH_PQKV;
  const unsigned short* PWOA = P16 + SH_PWOA;
  const float* BQKV = ws + FL_BQKV;
  const float* BO4 = ws + FL_BO4;
  const unsigned short* PA1 = P16 + SH_PA1;
  const unsigned short* PB2 = P16 + SH_PB2;

  const int lane = threadIdx.x & 63;
  const int bl = lane / 9;     // 0..7 (7 == pad lane 63)
  const int s = lane - bl * 9;
  const long wb = (long)blockIdx.x;  // one wave per block
  const long bb = wb * 7 + bl;
  const bool active = (bl < 7) && (bb < B_TOT);

  char* slab = smem;
  const int cl = lane & 15;
  const int g = lane >> 4;
  const f32x4 zero4 = {0.f, 0.f, 0.f, 0.f};

  float x[20];  // residual through LN1 (regs)

  // ---------------- stage X bf16 rows (zeros 40..63 for frag pad) ------------
  {
    if (active) {
      const float4* xr = (const float4*)(X + bb * (S * D) + s * D);
#pragma unroll
      for (int i = 0; i < 5; ++i) {
        float4 t = xr[i];
        x[4 * i + 0] = t.x; x[4 * i + 1] = t.y; x[4 * i + 2] = t.z; x[4 * i + 3] = t.w;
      }
    } else {
#pragma unroll
      for (int i = 0; i < 20; ++i) x[i] = 0.f;
    }
    char* r = slab + RA + lane * 72;
#pragma unroll
    for (int i = 0; i < 5; ++i)
      *(uint2*)(r + 8 * i) = make_uint2(cvt2(x[4 * i], x[4 * i + 1]),
                                        cvt2(x[4 * i + 2], x[4 * i + 3]));
    *(uint2*)(r + 40) = make_uint2(0u, 0u);
    *(uint2*)(r + 48) = make_uint2(0u, 0u);
    *(uint2*)(r + 56) = make_uint2(0u, 0u);
  }
  FENCE();

  // ---------------- X B-frags ------------------------------------------------
  bf16x8 xfB[4];
#pragma unroll
  for (int rtc = 0; rtc < 4; ++rtc)
    xfB[rtc] = *(const bf16x8*)(slab + RA + (rtc * 16 + cl) * 72 + g * 16);
  FENCE();  // frags read before q overlays X

  // ---------------- QKV MFMA (swapped), bias C-in, f16 unpadded scatter ------
#pragma unroll
  for (int ct = 0; ct < 4; ++ct) {
    bf16x8 wf = *(const bf16x8*)(PQKV + (size_t)(ct * 64 + lane) * 8);
    float4 bq4 = *(const float4*)(BQKV + ct * 16 + 4 * g);
    const f32x4 cin = {bq4.x, bq4.y, bq4.z, bq4.w};
    const int qd = ct * 4 + g;                 // j-quad 0..15
    const int mat = (qd >= 10) ? 2 : ((qd >= 5) ? 1 : 0);
    const int jc4 = qd - 5 * mat;              // quad within matrix 0..4
    const bool qv = qd < 15;
#pragma unroll
    for (int rtc = 0; rtc < 4; ++rtc) {
      f32x4 d = __builtin_amdgcn_mfma_f32_16x16x32_bf16(wf, xfB[rtc], cin, 0, 0, 0);
      if (qv) {
        const int row = rtc * 16 + cl;
        unsigned u0 = cvt2h(d[0], d[1]);
        unsigned u1 = cvt2h(d[2], d[3]);
        char* p = (mat == 0) ? (slab + RA + row * 72 + jc4 * 8)
                             : (slab + RB + row * 80 + ((mat == 2) ? 40 : 0) + jc4 * 8);
        *(uint2*)p = make_uint2(u0, u1);
      }
    }
  }
  FENCE();

  // ---------------- attention: unpadded packed-f16, no-max exp2 softmax -------
  // pairs p cover els (2p,2p+1); heads: h0 els0-4, h1 5-9, h2 10-14, h3 15-19
  float ctx[20];
  if (active) {
    h2u q2[10];
    {
      const uint2* qp = (const uint2*)(slab + RA + lane * 72);
#pragma unroll
      for (int i = 0; i < 5; ++i) { uint2 t = qp[i]; q2[2 * i].u = t.x; q2[2 * i + 1].u = t.y; }
    }
    float sc[4][9];
#pragma unroll
    for (int t = 0; t < 9; ++t) {
      h2u k2[10];
      const char* kp = slab + RB + (bl * 9 + t) * 80;
      {
        uint4 a = *(const uint4*)kp;          // 16B aligned (80|16)
        uint4 b = *(const uint4*)(kp + 16);
        uint2 c = *(const uint2*)(kp + 32);
        k2[0].u = a.x; k2[1].u = a.y; k2[2].u = a.z; k2[3].u = a.w;
        k2[4].u = b.x; k2[5].u = b.y; k2[6].u = b.z; k2[7].u = b.w;
        k2[8].u = c.x; k2[9].u = c.y;
      }
      __half2 a0 = __hmul2(q2[0].h, k2[0].h); a0 = __hfma2(q2[1].h, k2[1].h, a0);
      __half2 m2 = __hmul2(q2[2].h, k2[2].h);
      __half2 a1 = __hmul2(q2[3].h, k2[3].h); a1 = __hfma2(q2[4].h, k2[4].h, a1);
      __half2 a2 = __hmul2(q2[5].h, k2[5].h); a2 = __hfma2(q2[6].h, k2[6].h, a2);
      __half2 m7 = __hmul2(q2[7].h, k2[7].h);
      __half2 a3 = __hmul2(q2[8].h, k2[8].h); a3 = __hfma2(q2[9].h, k2[9].h, a3);
      sc[0][t] = __low2float(a0) + __high2float(a0) + __low2float(m2);
      sc[1][t] = __high2float(m2) + __low2float(a1) + __high2float(a1);
      sc[2][t] = __low2float(a2) + __high2float(a2) + __low2float(m7);
      sc[3][t] = __high2float(m7) + __low2float(a3) + __high2float(a3);
    }
    // scores already in exp2 domain (Wq pre-scaled by log2(e)/3); |score| << 1
    // so no max-subtraction needed (softmax is shift-invariant; no overflow).
    float inv4[4];
#pragma unroll
    for (int h = 0; h < 4; ++h) {
      float sum = 0.f;
#pragma unroll
      for (int t = 0; t < 9; ++t) {
        sc[h][t] = exp2f(sc[h][t]);
        sum += sc[h][t];
      }
      inv4[h] = 1.0f / sum;
    }
    h2u ctx2[10];
#pragma unroll
    for (int i = 0; i < 10; ++i) ctx2[i].u = 0u;
#pragma unroll
    for (int t = 0; t < 9; ++t) {
      h2u v2[10];
      const char* vp = slab + RB + (bl * 9 + t) * 80 + 40;
      {
        uint2 a = *(const uint2*)vp;          // 8-aligned
        uint4 b = *(const uint4*)(vp + 8);    // +48 ≡ 0 mod 16
        uint4 c = *(const uint4*)(vp + 24);
        v2[0].u = a.x; v2[1].u = a.y;
        v2[2].u = b.x; v2[3].u = b.y; v2[4].u = b.z; v2[5].u = b.w;
        v2[6].u = c.x; v2[7].u = c.y; v2[8].u = c.z; v2[9].u = c.w;
      }
      h2u p00, p11, p22, p33, m01, m23;
      p00.h = __float2half2_rn(sc[0][t]);
      p11.h = __float2half2_rn(sc[1][t]);
      p22.h = __float2half2_rn(sc[2][t]);
      p33.h = __float2half2_rn(sc[3][t]);
      m01.u = cvt2h(sc[0][t], sc[1][t]);
      m23.u = cvt2h(sc[2][t], sc[3][t]);
      ctx2[0].h = __hfma2(p00.h, v2[0].h, ctx2[0].h);
      ctx2[1].h = __hfma2(p00.h, v2[1].h, ctx2[1].h);
      ctx2[2].h = __hfma2(m01.h, v2[2].h, ctx2[2].h);
      ctx2[3].h = __hfma2(p11.h, v2[3].h, ctx2[3].h);
      ctx2[4].h = __hfma2(p11.h, v2[4].h, ctx2[4].h);
      ctx2[5].h = __hfma2(p22.h, v2[5].h, ctx2[5].h);
      ctx2[6].h = __hfma2(p22.h, v2[6].h, ctx2[6].h);
      ctx2[7].h = __hfma2(m23.h, v2[7].h, ctx2[7].h);
      ctx2[8].h = __hfma2(p33.h, v2[8].h, ctx2[8].h);
      ctx2[9].h = __hfma2(p33.h, v2[9].h, ctx2[9].h);
    }
#pragma unroll
    for (int p = 0; p < 10; ++p) {
      ctx[2 * p] = __low2float(ctx2[p].h) * inv4[(2 * p) / 5];
      ctx[2 * p + 1] = __high2float(ctx2[p].h) * inv4[(2 * p + 1) / 5];
    }
  }
  FENCE();  // k/v reads done before merged overlay of RB

  // ---------------- merged-ctx scatter (transpose quirk), stride 80 in RB ----
  if (active) {
    int m = s;  // merged linear index m = 9*w + s, w = 5h+dh
#pragma unroll
    for (int w = 0; w < 20; ++w) {
      int row = (m * 3277) >> 16;  // m/20 (m < 180)
      int col = m - 20 * row;
      *(unsigned short*)(slab + RB + (bl * 9 + row) * 80 + col * 2) = f2bf(ctx[w]);
      m += 9;
    }
  } else {
    *(uint4*)(slab + RB + lane * 80) = make_uint4(0u, 0u, 0u, 0u);
    *(uint4*)(slab + RB + lane * 80 + 16) = make_uint4(0u, 0u, 0u, 0u);
    *(uint2*)(slab + RB + lane * 80 + 32) = make_uint2(0u, 0u);
  }
  // zero-pad merged cols 20..31 (every lane owns row `lane`)
  *(uint2*)(slab + RB + lane * 80 + 40) = make_uint2(0u, 0u);
  *(uint4*)(slab + RB + lane * 80 + 48) = make_uint4(0u, 0u, 0u, 0u);
  FENCE();

  // ---------------- Wo MFMA (swapped), bias C-in, fp32 ao scatter ------------
  bf16x8 mfB[4];
#pragma unroll
  for (int rtc = 0; rtc < 4; ++rtc)
    mfB[rtc] = *(const bf16x8*)(slab + RB + (rtc * 16 + cl) * 80 + g * 16);
  FENCE();  // merged consumed before ao overlay
#pragma unroll
  for (int ct = 0; ct < 2; ++ct) {
    bf16x8 wof = *(const bf16x8*)(PWOA + (size_t)(ct * 64 + lane) * 8);
    float4 bo4 = *(const float4*)(BO4 + ct * 16 + 4 * g);
    const f32x4 cin = {bo4.x, bo4.y, bo4.z, bo4.w};
    const int qd = ct * 4 + g;
    const bool qv = qd < 5;
#pragma unroll
    for (int rtc = 0; rtc < 4; ++rtc) {
      f32x4 d = __builtin_amdgcn_mfma_f32_16x16x32_bf16(wof, mfB[rtc], cin, 0, 0, 0);
      if (qv) {
        const int row = rtc * 16 + cl;
        *(float4*)(slab + RB + row * 80 + qd * 16) = make_float4(d[0], d[1], d[2], d[3]);
      }
    }
  }
  FENCE();

  // ---------------- LN1 (ao fp32 from LDS; x from registers) -----------------
  float y[20];
  if (active) {
    float ao[20];
    {
      const float4* ap = (const float4*)(slab + RB + lane * 80);
#pragma unroll
      for (int i = 0; i < 5; ++i) {
        float4 t = ap[i];
        ao[4 * i] = t.x; ao[4 * i + 1] = t.y; ao[4 * i + 2] = t.z; ao[4 * i + 3] = t.w;
      }
    }
    float z[20];
#pragma unroll
    for (int d = 0; d < 20; ++d) z[d] = ao[d] + x[d];
    float t0 = 0.f;
#pragma unroll
    for (int d = 0; d < 20; ++d) t0 += z[d];
    float mean = t0 * (1.0f / 20.0f);
    float var = 0.f;
#pragma unroll
    for (int d = 0; d < 20; ++d) { z[d] -= mean; var += z[d] * z[d]; }
    float rs = rsqrtf(var * (1.0f / 20.0f) + EPS);
#pragma unroll
    for (int d = 0; d < 20; ++d) y[d] = z[d] * rs * g1[d] + b1[d];
  } else {
#pragma unroll
    for (int d = 0; d < 20; ++d) y[d] = 0.f;
  }
  FENCE();  // q dead; safe to overwrite RA with Y

  // ---------------- stage Y bf16 rows + re-zero pad (q overlaid it) ----------
  {
    char* r = slab + RA + lane * 72;
#pragma unroll
    for (int i = 0; i < 5; ++i)
      *(uint2*)(r + 8 * i) = make_uint2(cvt2(y[4 * i], y[4 * i + 1]),
                                        cvt2(y[4 * i + 2], y[4 * i + 3]));
    *(uint2*)(r + 40) = make_uint2(0u, 0u);
    *(uint2*)(r + 48) = make_uint2(0u, 0u);
    *(uint2*)(r + 56) = make_uint2(0u, 0u);
  }
  FENCE();

  // ---------------- FFN via MFMA: bf16 FFN1 -> pk_max relu -> f16 FFN2 -------
  bf16x8 ytf[4];
#pragma unroll
  for (int rt = 0; rt < 4; ++rt)
    ytf[rt] = *(const bf16x8*)(slab + RA + (rt * 16 + cl) * 72 + g * 16);

  f32x4 acc[4][2];
#pragma unroll
  for (int rt = 0; rt < 4; ++rt) { acc[rt][0] = zero4; acc[rt][1] = zero4; }

  const unsigned zz = 0u;
  for (int ch = 0; ch < 4; ++ch) {
#pragma unroll
    for (int q2 = 0; q2 < 4; ++q2) {
      const int fb = ch * 8 + q2 * 2;
      bf16x8 aw0 = *(const bf16x8*)(PA1 + (size_t)(fb * 64 + lane) * 8);
      bf16x8 aw1 = *(const bf16x8*)(PA1 + (size_t)((fb + 1) * 64 + lane) * 8);
      f16x8 bw0 = *(const f16x8*)(PB2 + (size_t)(fb * 64 + lane) * 8);
      f16x8 bw1 = *(const f16x8*)(PB2 + (size_t)((fb + 1) * 64 + lane) * 8);
#pragma unroll
      for (int rt = 0; rt < 4; ++rt) {
        f32x4 d0 = __builtin_amdgcn_mfma_f32_16x16x32_bf16(aw0, ytf[rt], zero4, 0, 0, 0);
        f32x4 d1 = __builtin_amdgcn_mfma_f32_16x16x32_bf16(aw1, ytf[rt], zero4, 0, 0, 0);
        union { f16x8 v; unsigned uu[4]; } af;
        af.uu[0] = pkmax0(cvt2h(d0[0], d0[1]), zz);
        af.uu[1] = pkmax0(cvt2h(d0[2], d0[3]), zz);
        af.uu[2] = pkmax0(cvt2h(d1[0], d1[1]), zz);
        af.uu[3] = pkmax0(cvt2h(d1[2], d1[3]), zz);
        acc[rt][0] = __builtin_amdgcn_mfma_f32_16x16x32_f16(af.v, bw0, acc[rt][0], 0, 0, 0);
        acc[rt][1] = __builtin_amdgcn_mfma_f32_16x16x32_f16(af.v, bw1, acc[rt][1], 0, 0, 0);
      }
    }
  }

  // ---------------- LN2 transposed: ff -> LDS, per-lane LN, coalesced store --
#pragma unroll
  for (int rt = 0; rt < 4; ++rt) {
#pragma unroll
    for (int r = 0; r < 4; ++r) {
      const int rrow = rt * 16 + 4 * g + r;
      *(float*)(slab + RB + rrow * 80 + cl * 4) = acc[rt][0][r];
      if (cl < 4) *(float*)(slab + RB + rrow * 80 + 64 + cl * 4) = acc[rt][1][r];
    }
  }
  FENCE();

  if (active) {
    float z[20];
    {
      const float4* fp = (const float4*)(slab + RB + lane * 80);
#pragma unroll
      for (int i = 0; i < 5; ++i) {
        float4 t = fp[i];
        z[4 * i] = t.x; z[4 * i + 1] = t.y; z[4 * i + 2] = t.z; z[4 * i + 3] = t.w;
      }
    }
    // residual y from registers
    float t0 = 0.f;
#pragma unroll
    for (int d = 0; d < 20; ++d) { z[d] += y[d]; t0 += z[d]; }
    float mean = t0 * (1.0f / 20.0f);
    float var = 0.f;
#pragma unroll
    for (int d = 0; d < 20; ++d) { z[d] -= mean; var += z[d] * z[d]; }
    float rs = rsqrtf(var * (1.0f / 20.0f) + EPS);
    float o[20];
#pragma unroll
    for (int d = 0; d < 20; ++d) o[d] = z[d] * rs * g2[d] + b2[d];
    float4* op = (float4*)(Out + (wb * 63 + lane) * 20);
#pragma unroll
    for (int i = 0; i < 5; ++i)
      op[i] = make_float4(o[4 * i], o[4 * i + 1], o[4 * i + 2], o[4 * i + 3]);
  }
}

extern "C" void kernel_launch(void* const* d_in, const int* in_sizes, int n_in,
                              void* d_out, int out_size, void* d_ws, size_t ws_size,
                              hipStream_t stream) {
  const float* X  = (const float*)d_in[0];
  const float* Wq = (const float*)d_in[1];
  const float* bq = (const float*)d_in[2];
  const float* Wk = (const float*)d_in[3];
  const float* bk = (const float*)d_in[4];
  const float* Wv = (const float*)d_in[5];
  const float* bv = (const float*)d_in[6];
  const float* Wo = (const float*)d_in[7];
  const float* bo = (const float*)d_in[8];
  const float* g1 = (const float*)d_in[9];
  const float* b1 = (const float*)d_in[10];
  const float* W1 = (const float*)d_in[11];
  const float* W2 = (const float*)d_in[12];
  const float* g2 = (const float*)d_in[13];
  const float* b2 = (const float*)d_in[14];
  float* Out = (float*)d_out;
  float* ws = (float*)d_ws;

  prep_kernel<<<144, 256, 0, stream>>>(Wq, Wk, Wv, Wo, W1, W2, bq, bk, bv, bo, ws);

  // one wave per block, 7 batch elements per wave
  int nblocks = (B_TOT + 6) / 7;  // 9363
  encoder_kernel<<<nblocks, 64, 0, stream>>>(X, ws, g1, b1, g2, b2, Out);
}